// Round 7
// baseline (239.537 us; speedup 1.0000x reference)
//
#include <hip/hip_runtime.h>
#include <hip/hip_bf16.h>

// NBFNet-cluttr forward.
// Algebra exploited:
//  - hidden rows only consumed through cosine sims -> per-row positive scale cancels ->
//    attention denominator dropped (out = M.B unnormalized). Exact.
//  - layer-0 q is ONE constant row qc except node 0. R15: the node-0 correction
//    (in-edges with src==0) touches only ~E/N ~= 16 nodes globally -> dropped from
//    the GEMM: hist is K=32 (18 used), and patch_kernel recomputes q for flagged
//    nodes (list built in ell). R16: patch one wave/list entry (serial 1-block form
//    was 79.5us at 0.01% occupancy -- single-wave serialization is the cardinal sin).
//  - node_pass fused into GEMM epilogue (Y tile stays in LDS; Y never hits HBM).
//  - last layer computed for tail indices only; sims written straight to d_out.
//  - edge index: fixed-width ELL (64 slots/node). R18: SINGLE-PASS build -- one
//    thread per edge, plain device atomicAdd on cur[d]. Rationale: CDNA4 device-
//    scope atomics execute memory-side (per-XCD L2s aren't cross-coherent), so
//    R10's partition->XCD affinity bought nothing for the atomics while paying
//    8x dst re-reads (25.6MB) + 8x waves (87.5% early-exit). R17 nt loads kept
//    (null in partitioned form; harmless). ELL slot ORDER changes vs partitioned:
//    downstream hist/scatter are order-invariant sums. Exact.
//    R8's 10x regression was TICKET serialization, not plain atomics.
//    Degrees Poisson(16): 64 slots = +12sigma; overflow drops.
//  - scatter: 1 wave/node, 3 private LDS slices (15.6KB; R5: 6 slices halved
//    occupancy); 6 edges in flight per 18-lane sub (R15); M write-out half2.
//  - GEMM [rows x K]x[K x 128] fp16 MFMA 16x16x32 fp32-acc; rel err ~5e-4 << 1.78e-2.
//  - Ledger: best 232.6us (R5); R6 nt-loads null (+3.1, noise). Fixed harness poison
//    ~89us (2x44.5 fills in-window); controllable chain ~143us: ell ~40 (this round's
//    target), scatter ~30, hist ~18, gemm1 ~25, prep ~10, rest ~15.
//  - 9 dispatches: prep, ell, hist, gemm0, patch, scatter, gemm1, scatter, gemm2.

#define N_NODES 50000
#define H 128
#define P 18
#define RP 324
#define KPAD 352   // 11 * 32
#define K0PAD 32   // layer-0 histogram GEMM K (18 used; R15)
#define ELLW 64    // ELL slots per node
#define PREP_MAIN_BLOCKS 384   // ceil((2*H*KPAD + H*64)/256) = 98304/256
#define N0CAP 1024             // src==0 edge list capacity (E[n0]=16)

typedef _Float16 half8 __attribute__((ext_vector_type(8)));
typedef _Float16 half2v __attribute__((ext_vector_type(2)));
typedef float floatx4 __attribute__((ext_vector_type(4)));

// Single-pass ELL build (R18): one thread per edge, memory-side atomics.
// Also appends src==0 edges to n0list (~16 total) for the layer-0 patch.
__global__ __launch_bounds__(256) void ell_kernel(const int* __restrict__ src,
                                                  const int* __restrict__ dst,
                                                  const int* __restrict__ etype,
                                                  unsigned* __restrict__ cur,
                                                  unsigned* __restrict__ ep,
                                                  unsigned* __restrict__ n0list, int E) {
  int i = blockIdx.x * 256 + threadIdx.x;
  if (i >= E) return;
  int d = __builtin_nontemporal_load(&dst[i]);
  int s = __builtin_nontemporal_load(&src[i]);
  int r = __builtin_nontemporal_load(&etype[i]);
  unsigned pos = atomicAdd(&cur[d], 1u);
  if (pos < ELLW)  // Poisson(16): overflow ~impossible; drop, never corrupt
    ep[(size_t)d * ELLW + pos] = (unsigned)s | ((unsigned)r << 20);
  if (s == 0) {  // ~E/N = 16 edges graph-wide
    unsigned ix = atomicAdd(&cur[N_NODES], 1u);
    if (ix < N0CAP) n0list[ix] = (unsigned)d | ((unsigned)r << 20);
  }
}

// Fused prep: blocks < PREP_MAIN_BLOCKS do {cur+n0cnt zero, Btg transpose, Btl0/BtD
// fold (with inline per-wave q0 row)}; blocks >= do pN normalization (4 rows/blk).
__global__ __launch_bounds__(256) void prep_kernel(const float* __restrict__ multi,
                                                   const float* __restrict__ proto,
                                                   const float* __restrict__ semb,
                                                   float* __restrict__ pN,
                                                   _Float16* __restrict__ Btg,
                                                   _Float16* __restrict__ Btl0,
                                                   _Float16* __restrict__ BtD,
                                                   unsigned* __restrict__ cur) {
  int bid = blockIdx.x;
  if (bid >= PREP_MAIN_BLOCKS) {
    // normalize the 54 prototype rows: 4 waves/block, 1 row/wave
    int wave = threadIdx.x >> 6, l = threadIdx.x & 63;
    int row = (bid - PREP_MAIN_BLOCKS) * 4 + wave;
    if (row >= 54) return;
    float a = proto[row * H + l], b = proto[row * H + 64 + l];
    float ss = a * a + b * b;
    for (int m = 32; m > 0; m >>= 1) ss += __shfl_xor(ss, m, 64);
    float inv = 1.f / fmaxf(sqrtf(ss), 1e-12f);
    pN[row * H + l] = a * inv;
    pN[row * H + 64 + l] = b * inv;
    return;
  }
  int idx = bid * 256 + threadIdx.x;
  if (idx <= N_NODES) cur[idx] = 0u;  // includes cur[N_NODES] = n0 count
  if (idx < 2 * H * KPAD) {  // Btg[l-1][h][k] = multi[l][k][h], k-pad to 352
    int l = idx / (H * KPAD), rem = idx - l * (H * KPAD);
    int h = rem / KPAD, k = rem - h * KPAD;
    const float* B = multi + (size_t)(l + 1) * RP * H;
    Btg[idx] = (k < RP) ? (_Float16)B[k * H + h] : (_Float16)0.f;
    return;
  }
  int idx2 = idx - 2 * H * KPAD;  // 2*H*KPAD = 90112, wave-aligned
  if (idx2 >= H * 64) return;     // cut at +8192, wave-aligned
  int h = idx2 >> 6, k = idx2 & 63;  // k == lane (90112 % 64 == 0)
  // inline q0 row (layer-0 q of node 0): full-butterfly -> every lane has all dq[p]
  float s0 = semb[k], s1 = semb[k + 64];
  float ssq = s0 * s0 + s1 * s1;
  float dq[P];
#pragma unroll
  for (int p = 0; p < P; p++) {
    float a = proto[p * H + k], b = proto[p * H + 64 + k];
    float rn = a * a + b * b;
    for (int m = 32; m > 0; m >>= 1) rn += __shfl_xor(rn, m, 64);
    float rinv = 1.f / fmaxf(sqrtf(rn), 1e-12f);
    dq[p] = (s0 * a + s1 * b) * rinv;
  }
  for (int m = 1; m <= 32; m <<= 1) {
    ssq += __shfl_xor(ssq, m, 64);
#pragma unroll
    for (int p = 0; p < P; p++) dq[p] += __shfl_xor(dq[p], m, 64);
  }
  float inv = 1.f / fmaxf(sqrtf(ssq), 1e-12f);
  float sum = 0.f;
#pragma unroll
  for (int p = 0; p < P; p++) {
    dq[p] = __expf(dq[p] * inv - 1.f);  // sims in [-1,1]: constant max-shift is exact
    sum += dq[p];
  }
  float isum = 1.f / sum, ent = 0.f;
#pragma unroll
  for (int p = 0; p < P; p++) {
    dq[p] *= isum;
    ent -= dq[p] * __logf(dq[p] + 1e-8f);
  }
  float w = __expf(-ent);  // q0[p] = w * dq[p]
  float pr = 1.f / 18.f, ent0 = 0.f;
#pragma unroll
  for (int p = 0; p < P; p++) ent0 -= pr * __logf(pr + 1e-8f);
  float qc = __expf(-ent0) * pr;
  if (k < K0PAD) {  // C block: Btl0[h][k] = qc * sum_p multi0[(k,p)][h], k<18
    float v = 0.f;
    if (k < P) {
#pragma unroll
      for (int p = 0; p < P; p++) v += qc * multi[(k * P + p) * H + h];
    }
    Btl0[h * K0PAD + k] = (_Float16)v;
  } else if (k < K0PAD + P) {  // D block (patch): BtD[r][h] = (q0-qc).multi0[r][:][h]
    int r = k - K0PAD;
    float v = 0.f;
#pragma unroll
    for (int p = 0; p < P; p++) v += (w * dq[p] - qc) * multi[(r * P + p) * H + h];
    BtD[r * H + h] = (_Float16)v;
  }
}

// Layer-0 "scatter": per-node in-edge type histogram via wave ballots (K=32, 18 used).
// One node per wave (50K waves: latency-bound gather wants max TLP — R11 lesson).
__global__ __launch_bounds__(256) void hist_kernel(const unsigned* __restrict__ ep,
                                                   const unsigned* __restrict__ cur,
                                                   _Float16* __restrict__ M, int n) {
  int wave = threadIdx.x >> 6, lane = threadIdx.x & 63;
  int nd = blockIdx.x * 4 + wave;
  if (nd >= n) return;
  int cnt = (int)cur[nd];
  if (cnt > ELLW) cnt = ELLW;
  bool a = lane < cnt;
  unsigned pk = a ? ep[(size_t)nd * ELLW + lane] : 0xFFFFFFFFu;
  int r = (int)(pk >> 20);
  float creg = 0.f;
#pragma unroll
  for (int rr = 0; rr < P; rr++) {
    unsigned long long m = __ballot(a && (r == rr));
    if (lane == rr) creg = (float)__popcll(m);
  }
  if (lane < K0PAD) M[(size_t)nd * K0PAD + lane] = (_Float16)creg;  // lanes>=18 write 0
}

// Layer-0 patch: recompute q for the ~16 nodes with in-edges from node 0.
// One wave per list entry; first occurrence of each node wins.
__global__ __launch_bounds__(256) void patch_kernel(const unsigned* __restrict__ cur,
                                                    const unsigned* __restrict__ n0list,
                                                    const _Float16* __restrict__ M,
                                                    const _Float16* __restrict__ Btl0,
                                                    const _Float16* __restrict__ BtD,
                                                    const float* __restrict__ pN,
                                                    _Float16* __restrict__ q) {
  int n0 = (int)cur[N_NODES];
  if (n0 > N0CAP) n0 = N0CAP;
  int wave = threadIdx.x >> 6, lane = threadIdx.x & 63;
  int e = blockIdx.x * 4 + wave;
  if (e >= n0) return;
  unsigned pe = n0list[e];
  int d = (int)(pe & 0xFFFFFu);
  for (int e2 = 0; e2 < e; e2++)  // only the first occurrence of d proceeds
    if ((int)(n0list[e2] & 0xFFFFFu) == d) return;
  // base Y[d] = cnt . C   (exactly what gemm0's MFMA computed, fp32 FMA of fp16)
  float ya = 0.f, yb = 0.f;
#pragma unroll
  for (int r = 0; r < P; r++) {
    float c = (float)M[(size_t)d * K0PAD + r];
    ya += c * (float)Btl0[lane * K0PAD + r];
    yb += c * (float)Btl0[(lane + 64) * K0PAD + r];
  }
  // + corrections for every src==0 in-edge of d (scan whole list; n0 ~ 16)
  for (int e2 = e; e2 < n0; e2++) {
    unsigned p2 = n0list[e2];
    if ((int)(p2 & 0xFFFFFu) != d) continue;
    int r2 = (int)(p2 >> 20);
    ya += (float)BtD[r2 * H + lane];
    yb += (float)BtD[r2 * H + lane + 64];
  }
  // epilogue f: normalize, cosine sims vs layer-1 protos, softmax, entropy weight
  float ss = ya * ya + yb * yb;
  float dot[P];
#pragma unroll
  for (int p = 0; p < P; p++) dot[p] = ya * pN[p * H + lane] + yb * pN[p * H + lane + 64];
  for (int m = 1; m <= 32; m <<= 1) {
    ss += __shfl_xor(ss, m, 64);
#pragma unroll
    for (int p = 0; p < P; p++) dot[p] += __shfl_xor(dot[p], m, 64);
  }
  float inv = 1.f / fmaxf(sqrtf(ss), 1e-12f);
  float sum = 0.f;
#pragma unroll
  for (int p = 0; p < P; p++) {
    dot[p] = __expf(dot[p] * inv - 1.f);
    sum += dot[p];
  }
  float isum = 1.f / sum, ent = 0.f;
#pragma unroll
  for (int p = 0; p < P; p++) {
    dot[p] *= isum;
    ent -= dot[p] * __logf(dot[p] + 1e-8f);
  }
  float w = __expf(-ent);
  if (lane < P) q[(size_t)d * P + lane] = (_Float16)(w * dot[lane]);
}

// ELL scatter (layers >= 1): one wave per output row; 3 subs of 18 lanes, each with a
// private 324-float LDS slice; 6 edges in flight per sub (R15). q fp16 (36B/edge).
// tl==null: row t = node t. tl!=null: row t = node tl[t] (dups write identical rows).
__global__ __launch_bounds__(256) void scatter_kernel(const unsigned* __restrict__ ep,
                                                      const unsigned* __restrict__ cur,
                                                      const _Float16* __restrict__ q,
                                                      const int* __restrict__ tl,
                                                      _Float16* __restrict__ M, int n) {
  __shared__ float sl[4][3 * RP];  // 15.6 KB
  int wave = threadIdx.x >> 6, lane = threadIdx.x & 63;
  int t = blockIdx.x * 4 + wave;
  float* s0 = sl[wave];
  for (int i = lane; i < 3 * RP; i += 64) s0[i] = 0.f;
  int sub = lane / 18;  // 0,1,2 active; lanes 54-63 idle in the edge loop
  int j = lane - sub * 18;
  bool act = (sub < 3) && (t < n);
  int cnt = 0;
  size_t b = 0;
  if (t < n) {
    int nd = tl ? tl[t] : t;
    b = (size_t)nd * ELLW;
    cnt = (int)cur[nd];
    if (cnt > ELLW) cnt = ELLW;
  }
  float* ms = s0 + (sub < 3 ? sub : 0) * RP;
  for (int it = 0; it < cnt; it += 18) {
    bool aa[6];
    unsigned pk[6];
    float qv[6];
#pragma unroll
    for (int u = 0; u < 6; u++) {
      int e = it + 3 * u + sub;
      aa[u] = act && (e < cnt);
      pk[u] = aa[u] ? ep[b + e] : 0u;
    }
#pragma unroll
    for (int u = 0; u < 6; u++)
      qv[u] = aa[u] ? (float)q[(size_t)(pk[u] & 0xFFFFFu) * P + j] : 0.f;
#pragma unroll
    for (int u = 0; u < 6; u++)
      if (aa[u]) ms[(pk[u] >> 20) * P + j] += qv[u];
  }
  if (t < n) {
    // half2 write-out: 176 words/row; words 0..161 = data, 162..175 = zero pad
    for (int wd = lane; wd < RP / 2; wd += 64) {
      float2 x0 = *(const float2*)(s0 + 2 * wd);
      float2 x1 = *(const float2*)(s0 + RP + 2 * wd);
      float2 x2 = *(const float2*)(s0 + 2 * RP + 2 * wd);
      half2v hv;
      hv[0] = (_Float16)(x0.x + x1.x + x2.x);
      hv[1] = (_Float16)(x0.y + x1.y + x2.y);
      *(half2v*)(M + (size_t)t * KPAD + 2 * wd) = hv;
    }
    for (int wd = RP / 2 + lane; wd < KPAD / 2; wd += 64) {
      half2v z = {};
      *(half2v*)(M + (size_t)t * KPAD + 2 * wd) = z;
    }
  }
}

// fp16 MFMA GEMM, 64 rows x 128 cols per block, K = kpad (runtime, mult of 32).
// MODE 0: epilogue -> next-layer q (fp16, softmax+entropy).
// MODE 1: epilogue -> cosine sims straight into d_out (fp32; rows are tail indices).
template <int MODE>
__global__ __launch_bounds__(256) void gemm_kernel(const _Float16* __restrict__ M,
                                                   const _Float16* __restrict__ Bt,
                                                   const float* __restrict__ pN,
                                                   void* __restrict__ out_ptr, int n,
                                                   int kpad) {
  __shared__ float smem_f[64 * 132];  // Y tile (fp32, stride 132); staging aliases it
  _Float16* As = (_Float16*)smem_f;           // 64x32 halfs (4KB)
  _Float16* Bs = (_Float16*)(smem_f + 1024);  // 128x32 halfs (8KB)
  int tid = threadIdx.x;
  int wave = tid >> 6, lane = tid & 63;
  int m15 = lane & 15, quad = lane >> 4;
  int n0 = blockIdx.x * 64;
  floatx4 acc[4][2] = {};

  // prototypes sliced per k-quarter (stride 36 -> conflict-free broadcast reads).
  // slice width is P*32 = 576 (R4 bug: was decoded as 512).
  __shared__ float pns[4 * P * 36];
  for (int i = tid; i < 4 * P * 32; i += 256) {
    int s = i / (P * 32), r = i - s * (P * 32);
    int p = r >> 5, kk = r & 31;
    pns[s * (P * 36) + p * 36 + kk] = pN[p * H + s * 32 + kk];
  }

  for (int kt = 0; kt < (kpad >> 5); kt++) {
    int k0 = kt * 32;
    __syncthreads();
    {  // stage A: 64x32 halfs, one 16B load/thread
      int row = tid >> 2, kc = (tid & 3) * 8;
      int gr = n0 + row;
      half8 v = {};
      if (gr < n) v = *(const half8*)(M + (size_t)gr * kpad + k0 + kc);
      *(half8*)(As + row * 32 + kc) = v;
    }
    {  // stage B: 128x32 halfs, two 16B loads/thread
      int col = tid >> 1, kc = (tid & 1) * 16;
      const _Float16* srcp = Bt + (size_t)col * kpad + k0 + kc;
      *(half8*)(Bs + col * 32 + kc) = *(const half8*)srcp;
      *(half8*)(Bs + col * 32 + kc + 8) = *(const half8*)(srcp + 8);
    }
    __syncthreads();
    half8 bfrag0 = *(const half8*)(Bs + (wave * 32 + m15) * 32 + quad * 8);
    half8 bfrag1 = *(const half8*)(Bs + (wave * 32 + 16 + m15) * 32 + quad * 8);
#pragma unroll
    for (int mt = 0; mt < 4; mt++) {
      half8 afrag = *(const half8*)(As + (mt * 16 + m15) * 32 + quad * 8);
      acc[mt][0] = __builtin_amdgcn_mfma_f32_16x16x32_f16(afrag, bfrag0, acc[mt][0], 0, 0, 0);
      acc[mt][1] = __builtin_amdgcn_mfma_f32_16x16x32_f16(afrag, bfrag1, acc[mt][1], 0, 0, 0);
    }
  }
  // D mapping: col = lane&15 (+16 per second mfma), row = quad*4+reg  [HW-verified]
  __syncthreads();  // staging reads done before the Y tile overwrites As/Bs
#pragma unroll
  for (int mt = 0; mt < 4; mt++)
#pragma unroll
    for (int c = 0; c < 2; c++)
#pragma unroll
      for (int reg = 0; reg < 4; reg++)
        smem_f[(mt * 16 + quad * 4 + reg) * 132 + wave * 32 + c * 16 + m15] = acc[mt][c][reg];
  __syncthreads();
  // 4 threads per node, each owns a 32-wide k-slice of the Y row
  int node = tid >> 2, sub = tid & 3;
  int gnode = n0 + node;
  const float* trow = smem_f + node * 132 + sub * 32;
  const float* ps = pns + sub * (P * 36);
  float ss = 0.f;
  float dot[P];
#pragma unroll
  for (int p = 0; p < P; p++) dot[p] = 0.f;
#pragma unroll
  for (int k4 = 0; k4 < 8; k4++) {
    float4 y = *(const float4*)(trow + k4 * 4);
    ss += y.x * y.x + y.y * y.y + y.z * y.z + y.w * y.w;
#pragma unroll
    for (int p = 0; p < P; p++) {
      float4 b = *(const float4*)(ps + p * 36 + k4 * 4);
      dot[p] += y.x * b.x + y.y * b.y + y.z * b.z + y.w * b.w;
    }
  }
  for (int m = 1; m <= 2; m <<= 1) {  // reduce across the 4 subs
    ss += __shfl_xor(ss, m, 64);
#pragma unroll
    for (int p = 0; p < P; p++) dot[p] += __shfl_xor(dot[p], m, 64);
  }
  if (gnode < n) {
    float inv = 1.f / fmaxf(sqrtf(ss), 1e-12f);  // zero rows -> sims 0 (matches ref)
    if (MODE == 1) {
      float* outp = (float*)out_ptr;
      for (int p = sub; p < P; p += 4) outp[(size_t)gnode * P + p] = dot[p] * inv;
    } else {
      float sum = 0.f;
#pragma unroll
      for (int p = 0; p < P; p++) {
        dot[p] = __expf(dot[p] * inv - 1.f);  // sims in [-1,1]: constant shift is exact
        sum += dot[p];
      }
      float isum = 1.f / sum, ent = 0.f;
#pragma unroll
      for (int p = 0; p < P; p++) {
        dot[p] *= isum;
        ent -= dot[p] * __logf(dot[p] + 1e-8f);
      }
      float w = __expf(-ent);
      _Float16* qp = (_Float16*)out_ptr;
      for (int p = sub; p < P; p += 4) qp[(size_t)gnode * P + p] = (_Float16)(w * dot[p]);
    }
  }
}

extern "C" void kernel_launch(void* const* d_in, const int* in_sizes, int n_in,
                              void* d_out, int out_size, void* d_ws, size_t ws_size,
                              hipStream_t stream) {
  const int* eidx = (const int*)d_in[0];
  int E = in_sizes[0] / 2;
  const int* src = eidx;
  const int* dst = eidx + E;
  const int* etype = (const int*)d_in[1];
  const int* tails = (const int*)d_in[2];
  int T = in_sizes[2];
  const float* multi = (const float*)d_in[3];  // [L, 324, 128]
  const float* proto = (const float*)d_in[4];  // [L, 18, 128]
  const float* semb = (const float*)d_in[5];   // [128]
  float* out = (float*)d_out;

  char* w = (char*)d_ws;
  auto alloc = [&](size_t bytes) {
    char* p = w;
    w += (bytes + 255) & ~(size_t)255;
    return p;
  };
  _Float16* q = (_Float16*)alloc((size_t)N_NODES * P * 2);
  float* pNs = (float*)alloc((size_t)3 * P * H * 4);
  _Float16* Mg = (_Float16*)alloc((size_t)N_NODES * KPAD * 2);
  _Float16* Btg = (_Float16*)alloc((size_t)2 * H * KPAD * 2);
  _Float16* Btl0 = (_Float16*)alloc((size_t)H * K0PAD * 2);
  _Float16* BtD = (_Float16*)alloc((size_t)P * H * 2);
  unsigned* cur = (unsigned*)alloc((size_t)(N_NODES + 1) * 4);  // +1: n0 count
  unsigned* n0list = (unsigned*)alloc((size_t)N0CAP * 4);
  unsigned* ep = (unsigned*)alloc((size_t)N_NODES * ELLW * 4);  // 12.8 MB

  int eb = (E + 255) / 256;  // 3125

  // ---- fused prep: pN rows, Btg, Btl0(C)/BtD(D) (+inline q0), cur+n0 zeroing ----
  prep_kernel<<<PREP_MAIN_BLOCKS + 14, 256, 0, stream>>>(multi, proto, semb, pNs, Btg,
                                                         Btl0, BtD, cur);

  // ---- ELL edge index + src==0 list (single-pass, R18) ----
  ell_kernel<<<eb, 256, 0, stream>>>(src, dst, etype, cur, ep, n0list, E);

  // ---- layer 0: ballot histogram (K=32) + K=32 GEMM -> q, then parallel n0 patch ----
  hist_kernel<<<(N_NODES + 3) / 4, 256, 0, stream>>>(ep, cur, Mg, N_NODES);
  gemm_kernel<0><<<(N_NODES + 63) / 64, 256, 0, stream>>>(Mg, Btl0, pNs + (size_t)1 * P * H, q,
                                                          N_NODES, K0PAD);
  patch_kernel<<<(N0CAP + 3) / 4, 256, 0, stream>>>(cur, n0list, Mg, Btl0, BtD,
                                                    pNs + (size_t)1 * P * H, q);

  // ---- layer 1: full-node scatter + fused-q GEMM ----
  scatter_kernel<<<(N_NODES + 3) / 4, 256, 0, stream>>>(ep, cur, q, nullptr, Mg, N_NODES);
  gemm_kernel<0><<<(N_NODES + 63) / 64, 256, 0, stream>>>(Mg, Btg, pNs + (size_t)2 * P * H, q,
                                                          N_NODES, KPAD);

  // ---- layer 2: tails only (scatter rows indexed by tail position, GEMM -> d_out) ----
  scatter_kernel<<<(T + 3) / 4, 256, 0, stream>>>(ep, cur, q, tails, Mg, T);
  gemm_kernel<1><<<(T + 63) / 64, 256, 0, stream>>>(Mg, Btg + (size_t)H * KPAD,
                                                    pNs + (size_t)2 * P * H, out, T, KPAD);
}

// Round 8
// 230.902 us; speedup vs baseline: 1.0374x; 1.0374x over previous
//
#include <hip/hip_runtime.h>
#include <hip/hip_bf16.h>

// NBFNet-cluttr forward.
// Algebra exploited:
//  - hidden rows only consumed through cosine sims -> per-row positive scale cancels ->
//    attention denominator dropped (out = M.B unnormalized). Exact.
//  - layer 0 is a function of the 18-vector of per-type in-edge counts ONLY:
//    Y = cnt.C. R19: epilogue needs just dot_p = Y.pN1_p and ss = |Y|^2, which
//    collapse through 18x18 Grams G = C.pN1^T, S = C.C^T (precomputed fp32 in
//    prep's extra blocks) -> histq_kernel produces q DIRECTLY from ballots
//    (hist_kernel + gemm0 + the 3.2MB M roundtrip deleted).
//  - node-0 correction (src==0 in-edges, ~16 nodes) handled by patch_kernel:
//    one wave per n0list entry (R16; serial form was 79.5us), cnt re-balloted
//    from ep, full-H recompute via Btl0/BtD.
//  - node_pass fused into GEMM epilogue (Y tile stays in LDS; Y never hits HBM).
//  - last layer computed for tail indices only; sims written straight to d_out.
//  - edge index: fixed-width ELL (64 slots/node), R10 partitioned build (R19
//    reverts R18 single-pass: FETCH 37->4.9MB but dur 40->50us; WRITE_SIZE is
//    the invariant ~48MB ~= E x 64B line write-backs -- ell is scattered-store/
//    atomic bound, insensitive to read org. nt loads dropped (R6: null).
//    R8's 10x regression was ticket serialization; R14 4-edge/thread also null).
//    Degrees Poisson(16): 64 slots = +12sigma; overflow drops.
//  - scatter: 1 wave/node, 3 private LDS slices (15.6KB; R5: 6 slices halved
//    occupancy); 6 edges in flight per 18-lane sub (R15); M write-out half2.
//  - GEMM [rows x K]x[K x 128] fp16 MFMA 16x16x32 fp32-acc; rel err ~5e-4 << 1.78e-2.
//  - Ledger: best 232.6us (R5). Fixed harness poison ~89us (2x44.5 fills
//    in-window). Chain: ell ~40 (floor for this layout), scatter ~30, gemm1 ~25,
//    prep ~10, histq/patch/tails ~12. Dispatch gaps ~0-2us.
//  - 8 dispatches: prep, ell, histq, patch, scatter, gemm1, scatter, gemm2.

#define N_NODES 50000
#define H 128
#define P 18
#define RP 324
#define KPAD 352   // 11 * 32
#define K0PAD 32   // Btl0 row stride (18 used; patch only)
#define ELLW 64    // ELL slots per node
#define NPART 8
#define NODES_PER_PART 6250    // 50000 / 8
#define PREP_MAIN_BLOCKS 384   // ceil((2*H*KPAD + H*64)/256) = 98304/256
#define PREP_PN_BLOCKS 14      // 54 proto rows, 4/block
#define PREP_GS_BLOCKS 162     // 648 G/S entries, 4 waves/block
#define N0CAP 1024             // src==0 edge list capacity (E[n0]=16)

typedef _Float16 half8 __attribute__((ext_vector_type(8)));
typedef _Float16 half2v __attribute__((ext_vector_type(2)));
typedef float floatx4 __attribute__((ext_vector_type(4)));

// Partitioned ELL build (R5 form): block b -> partition b&7, edge chunk b>>3.
// Also appends src==0 edges to n0list (~16 total) for the layer-0 patch.
__global__ __launch_bounds__(256) void ell_kernel(const int* __restrict__ src,
                                                  const int* __restrict__ dst,
                                                  const int* __restrict__ etype,
                                                  unsigned* __restrict__ cur,
                                                  unsigned* __restrict__ ep,
                                                  unsigned* __restrict__ n0list, int E) {
  int part = blockIdx.x & (NPART - 1);
  int i = (blockIdx.x >> 3) * 256 + threadIdx.x;
  if (i >= E) return;
  int d = dst[i];
  int lo = part * NODES_PER_PART;
  if (d < lo || d >= lo + NODES_PER_PART) return;
  int s = src[i];
  int r = etype[i];
  unsigned pos = atomicAdd(&cur[d], 1u);
  if (pos < ELLW)  // Poisson(16): overflow ~impossible; drop, never corrupt
    ep[(size_t)d * ELLW + pos] = (unsigned)s | ((unsigned)r << 20);
  if (s == 0) {  // ~E/N = 16 edges graph-wide
    unsigned ix = atomicAdd(&cur[N_NODES], 1u);
    if (ix < N0CAP) n0list[ix] = (unsigned)d | ((unsigned)r << 20);
  }
}

// Fused prep:
//  blocks < PREP_MAIN_BLOCKS: cur+n0cnt zero, Btg transpose, Btl0/BtD fold
//    (inline per-wave q0 row).
//  next PREP_PN_BLOCKS: pN normalization (4 rows/block).
//  next PREP_GS_BLOCKS: G/S Grams, fp32, 1 entry/wave (reads raw multi/proto only).
__global__ __launch_bounds__(256) void prep_kernel(const float* __restrict__ multi,
                                                   const float* __restrict__ proto,
                                                   const float* __restrict__ semb,
                                                   float* __restrict__ pN,
                                                   _Float16* __restrict__ Btg,
                                                   _Float16* __restrict__ Btl0,
                                                   _Float16* __restrict__ BtD,
                                                   float* __restrict__ GS,
                                                   unsigned* __restrict__ cur) {
  int bid = blockIdx.x;
  if (bid >= PREP_MAIN_BLOCKS + PREP_PN_BLOCKS) {
    // G[r][p] = sum_h C[r][h]*pN1[p][h];  S[r][r2] = sum_h C[r][h]*C[r2][h]
    // C[k][h] = qc * sum_q multi0[(k*18+q)*H + h]   (fp32 throughout)
    int wave = threadIdx.x >> 6, lane = threadIdx.x & 63;
    int pi = (bid - PREP_MAIN_BLOCKS - PREP_PN_BLOCKS) * 4 + wave;
    if (pi >= 648) return;
    float pr = 1.f / 18.f, ent0 = 0.f;
#pragma unroll
    for (int p = 0; p < P; p++) ent0 -= pr * __logf(pr + 1e-8f);
    float qc = __expf(-ent0) * pr;
    bool isG = pi < 324;
    int rr = isG ? pi / P : (pi - 324) / P;
    int cc = isG ? pi - rr * P : (pi - 324) - rr * P;
    float ca = 0.f, cb = 0.f;
#pragma unroll
    for (int q2 = 0; q2 < P; q2++) {
      ca += multi[(rr * P + q2) * H + lane];
      cb += multi[(rr * P + q2) * H + lane + 64];
    }
    ca *= qc; cb *= qc;
    float xa, xb, rn = 0.f;
    if (isG) {
      xa = proto[(P + cc) * H + lane];       // layer-1 prototypes
      xb = proto[(P + cc) * H + lane + 64];
      rn = xa * xa + xb * xb;
    } else {
      xa = 0.f; xb = 0.f;
#pragma unroll
      for (int q2 = 0; q2 < P; q2++) {
        xa += multi[(cc * P + q2) * H + lane];
        xb += multi[(cc * P + q2) * H + lane + 64];
      }
      xa *= qc; xb *= qc;
    }
    float dotp = ca * xa + cb * xb;
    for (int m = 32; m > 0; m >>= 1) {
      dotp += __shfl_xor(dotp, m, 64);
      rn += __shfl_xor(rn, m, 64);
    }
    float val = isG ? dotp / fmaxf(sqrtf(rn), 1e-12f) : dotp;
    if (lane == 0) GS[pi] = val;
    return;
  }
  if (bid >= PREP_MAIN_BLOCKS) {
    // normalize the 54 prototype rows: 4 waves/block, 1 row/wave
    int wave = threadIdx.x >> 6, l = threadIdx.x & 63;
    int row = (bid - PREP_MAIN_BLOCKS) * 4 + wave;
    if (row >= 54) return;
    float a = proto[row * H + l], b = proto[row * H + 64 + l];
    float ss = a * a + b * b;
    for (int m = 32; m > 0; m >>= 1) ss += __shfl_xor(ss, m, 64);
    float inv = 1.f / fmaxf(sqrtf(ss), 1e-12f);
    pN[row * H + l] = a * inv;
    pN[row * H + 64 + l] = b * inv;
    return;
  }
  int idx = bid * 256 + threadIdx.x;
  if (idx <= N_NODES) cur[idx] = 0u;  // includes cur[N_NODES] = n0 count
  if (idx < 2 * H * KPAD) {  // Btg[l-1][h][k] = multi[l][k][h], k-pad to 352
    int l = idx / (H * KPAD), rem = idx - l * (H * KPAD);
    int h = rem / KPAD, k = rem - h * KPAD;
    const float* B = multi + (size_t)(l + 1) * RP * H;
    Btg[idx] = (k < RP) ? (_Float16)B[k * H + h] : (_Float16)0.f;
    return;
  }
  int idx2 = idx - 2 * H * KPAD;  // 2*H*KPAD = 90112, wave-aligned
  if (idx2 >= H * 64) return;     // cut at +8192, wave-aligned
  int h = idx2 >> 6, k = idx2 & 63;  // k == lane (90112 % 64 == 0)
  // inline q0 row (layer-0 q of node 0): full-butterfly -> every lane has all dq[p]
  float s0 = semb[k], s1 = semb[k + 64];
  float ssq = s0 * s0 + s1 * s1;
  float dq[P];
#pragma unroll
  for (int p = 0; p < P; p++) {
    float a = proto[p * H + k], b = proto[p * H + 64 + k];
    float rn = a * a + b * b;
    for (int m = 32; m > 0; m >>= 1) rn += __shfl_xor(rn, m, 64);
    float rinv = 1.f / fmaxf(sqrtf(rn), 1e-12f);
    dq[p] = (s0 * a + s1 * b) * rinv;
  }
  for (int m = 1; m <= 32; m <<= 1) {
    ssq += __shfl_xor(ssq, m, 64);
#pragma unroll
    for (int p = 0; p < P; p++) dq[p] += __shfl_xor(dq[p], m, 64);
  }
  float inv = 1.f / fmaxf(sqrtf(ssq), 1e-12f);
  float sum = 0.f;
#pragma unroll
  for (int p = 0; p < P; p++) {
    dq[p] = __expf(dq[p] * inv - 1.f);  // sims in [-1,1]: constant max-shift is exact
    sum += dq[p];
  }
  float isum = 1.f / sum, ent = 0.f;
#pragma unroll
  for (int p = 0; p < P; p++) {
    dq[p] *= isum;
    ent -= dq[p] * __logf(dq[p] + 1e-8f);
  }
  float w = __expf(-ent);  // q0[p] = w * dq[p]
  float pr = 1.f / 18.f, ent0 = 0.f;
#pragma unroll
  for (int p = 0; p < P; p++) ent0 -= pr * __logf(pr + 1e-8f);
  float qc = __expf(-ent0) * pr;
  if (k < K0PAD) {  // C block: Btl0[h][k] = qc * sum_p multi0[(k,p)][h], k<18
    float v = 0.f;
    if (k < P) {
#pragma unroll
      for (int p = 0; p < P; p++) v += qc * multi[(k * P + p) * H + h];
    }
    Btl0[h * K0PAD + k] = (_Float16)v;
  } else if (k < K0PAD + P) {  // D block (patch): BtD[r][h] = (q0-qc).multi0[r][:][h]
    int r = k - K0PAD;
    float v = 0.f;
#pragma unroll
    for (int p = 0; p < P; p++) v += (w * dq[p] - qc) * multi[(r * P + p) * H + h];
    BtD[r * H + h] = (_Float16)v;
  }
}

// Layer-0 fused hist+epilogue (R19): ballots -> cnt in lanes; dot_p/ss via the
// 18x18 Grams; softmax+entropy in-wave; writes q directly. One node per wave.
__global__ __launch_bounds__(256) void histq_kernel(const unsigned* __restrict__ ep,
                                                    const unsigned* __restrict__ cur,
                                                    const float* __restrict__ GS,
                                                    _Float16* __restrict__ q, int n) {
  __shared__ float gs[648];
  for (int i = threadIdx.x; i < 648; i += 256) gs[i] = GS[i];
  __syncthreads();
  int wave = threadIdx.x >> 6, lane = threadIdx.x & 63;
  int nd = blockIdx.x * 4 + wave;
  if (nd >= n) return;
  int cnt = (int)cur[nd];
  if (cnt > ELLW) cnt = ELLW;
  bool a = lane < cnt;
  unsigned pk = a ? ep[(size_t)nd * ELLW + lane] : 0xFFFFFFFFu;
  int r = (int)(pk >> 20);
  float creg = 0.f;
#pragma unroll
  for (int rr = 0; rr < P; rr++) {
    unsigned long long m = __ballot(a && (r == rr));
    if (lane == rr) creg = (float)__popcll(m);
  }
  // lane p: dot_p = sum_r cnt_r G[r][p];  lane r: t_r = sum_r' cnt_r' S[r'][r]
  float dot = 0.f, t = 0.f;
#pragma unroll
  for (int rr = 0; rr < P; rr++) {
    float c = __shfl(creg, rr, 64);
    if (lane < P) {
      dot += c * gs[rr * P + lane];
      t += c * gs[324 + rr * P + lane];
    }
  }
  float u = (lane < P) ? creg * t : 0.f;  // ss = cnt^T S cnt
  for (int m = 1; m <= 16; m <<= 1) u += __shfl_xor(u, m, 32);
  float ss = u;
  float inv = 1.f / fmaxf(sqrtf(ss), 1e-12f);
  float e = (lane < P) ? __expf(dot * inv - 1.f) : 0.f;  // shift by const 1: exact
  float sum = e;
  for (int m = 1; m <= 16; m <<= 1) sum += __shfl_xor(sum, m, 32);
  float prb = e / sum;
  float term = (lane < P) ? prb * __logf(prb + 1e-8f) : 0.f;
  float ent = term;
  for (int m = 1; m <= 16; m <<= 1) ent += __shfl_xor(ent, m, 32);
  float w = __expf(ent);  // w = exp(-(-sum)) ; ent accumulated = -entropy
  if (lane < P) q[(size_t)nd * P + lane] = (_Float16)(w * prb);
}

// Layer-0 patch: recompute q for the ~16 nodes with in-edges from node 0.
// One wave per list entry; first occurrence wins; cnt re-balloted from ep (R19).
__global__ __launch_bounds__(256) void patch_kernel(const unsigned* __restrict__ cur,
                                                    const unsigned* __restrict__ n0list,
                                                    const unsigned* __restrict__ ep,
                                                    const _Float16* __restrict__ Btl0,
                                                    const _Float16* __restrict__ BtD,
                                                    const float* __restrict__ pN,
                                                    _Float16* __restrict__ q) {
  int n0 = (int)cur[N_NODES];
  if (n0 > N0CAP) n0 = N0CAP;
  int wave = threadIdx.x >> 6, lane = threadIdx.x & 63;
  int e = blockIdx.x * 4 + wave;
  if (e >= n0) return;
  unsigned pe = n0list[e];
  int d = (int)(pe & 0xFFFFFu);
  for (int e2 = 0; e2 < e; e2++)  // only the first occurrence of d proceeds
    if ((int)(n0list[e2] & 0xFFFFFu) == d) return;
  // re-ballot this node's type counts from its ep row
  int cnt = (int)cur[d];
  if (cnt > ELLW) cnt = ELLW;
  bool a = lane < cnt;
  unsigned pk2 = a ? ep[(size_t)d * ELLW + lane] : 0xFFFFFFFFu;
  int rr0 = (int)(pk2 >> 20);
  float creg = 0.f;
#pragma unroll
  for (int rr = 0; rr < P; rr++) {
    unsigned long long m = __ballot(a && (rr0 == rr));
    if (lane == rr) creg = (float)__popcll(m);
  }
  // base Y[d] = cnt . C  (h = lane, lane+64)
  float ya = 0.f, yb = 0.f;
#pragma unroll
  for (int rr = 0; rr < P; rr++) {
    float c = __shfl(creg, rr, 64);
    ya += c * (float)Btl0[lane * K0PAD + rr];
    yb += c * (float)Btl0[(lane + 64) * K0PAD + rr];
  }
  // + corrections for every src==0 in-edge of d (scan whole list; n0 ~ 16)
  for (int e2 = e; e2 < n0; e2++) {
    unsigned p2 = n0list[e2];
    if ((int)(p2 & 0xFFFFFu) != d) continue;
    int r2 = (int)(p2 >> 20);
    ya += (float)BtD[r2 * H + lane];
    yb += (float)BtD[r2 * H + lane + 64];
  }
  // epilogue f: normalize, cosine sims vs layer-1 protos, softmax, entropy weight
  float ss = ya * ya + yb * yb;
  float dot[P];
#pragma unroll
  for (int p = 0; p < P; p++) dot[p] = ya * pN[p * H + lane] + yb * pN[p * H + lane + 64];
  for (int m = 1; m <= 32; m <<= 1) {
    ss += __shfl_xor(ss, m, 64);
#pragma unroll
    for (int p = 0; p < P; p++) dot[p] += __shfl_xor(dot[p], m, 64);
  }
  float inv = 1.f / fmaxf(sqrtf(ss), 1e-12f);
  float sum = 0.f;
#pragma unroll
  for (int p = 0; p < P; p++) {
    dot[p] = __expf(dot[p] * inv - 1.f);
    sum += dot[p];
  }
  float isum = 1.f / sum, ent = 0.f;
#pragma unroll
  for (int p = 0; p < P; p++) {
    dot[p] *= isum;
    ent -= dot[p] * __logf(dot[p] + 1e-8f);
  }
  float w = __expf(-ent);
  if (lane < P) q[(size_t)d * P + lane] = (_Float16)(w * dot[lane]);
}

// ELL scatter (layers >= 1): one wave per output row; 3 subs of 18 lanes, each with a
// private 324-float LDS slice; 6 edges in flight per sub (R15). q fp16 (36B/edge).
// tl==null: row t = node t. tl!=null: row t = node tl[t] (dups write identical rows).
__global__ __launch_bounds__(256) void scatter_kernel(const unsigned* __restrict__ ep,
                                                      const unsigned* __restrict__ cur,
                                                      const _Float16* __restrict__ q,
                                                      const int* __restrict__ tl,
                                                      _Float16* __restrict__ M, int n) {
  __shared__ float sl[4][3 * RP];  // 15.6 KB
  int wave = threadIdx.x >> 6, lane = threadIdx.x & 63;
  int t = blockIdx.x * 4 + wave;
  float* s0 = sl[wave];
  for (int i = lane; i < 3 * RP; i += 64) s0[i] = 0.f;
  int sub = lane / 18;  // 0,1,2 active; lanes 54-63 idle in the edge loop
  int j = lane - sub * 18;
  bool act = (sub < 3) && (t < n);
  int cnt = 0;
  size_t b = 0;
  if (t < n) {
    int nd = tl ? tl[t] : t;
    b = (size_t)nd * ELLW;
    cnt = (int)cur[nd];
    if (cnt > ELLW) cnt = ELLW;
  }
  float* ms = s0 + (sub < 3 ? sub : 0) * RP;
  for (int it = 0; it < cnt; it += 18) {
    bool aa[6];
    unsigned pk[6];
    float qv[6];
#pragma unroll
    for (int u = 0; u < 6; u++) {
      int e = it + 3 * u + sub;
      aa[u] = act && (e < cnt);
      pk[u] = aa[u] ? ep[b + e] : 0u;
    }
#pragma unroll
    for (int u = 0; u < 6; u++)
      qv[u] = aa[u] ? (float)q[(size_t)(pk[u] & 0xFFFFFu) * P + j] : 0.f;
#pragma unroll
    for (int u = 0; u < 6; u++)
      if (aa[u]) ms[(pk[u] >> 20) * P + j] += qv[u];
  }
  if (t < n) {
    // half2 write-out: 176 words/row; words 0..161 = data, 162..175 = zero pad
    for (int wd = lane; wd < RP / 2; wd += 64) {
      float2 x0 = *(const float2*)(s0 + 2 * wd);
      float2 x1 = *(const float2*)(s0 + RP + 2 * wd);
      float2 x2 = *(const float2*)(s0 + 2 * RP + 2 * wd);
      half2v hv;
      hv[0] = (_Float16)(x0.x + x1.x + x2.x);
      hv[1] = (_Float16)(x0.y + x1.y + x2.y);
      *(half2v*)(M + (size_t)t * KPAD + 2 * wd) = hv;
    }
    for (int wd = RP / 2 + lane; wd < KPAD / 2; wd += 64) {
      half2v z = {};
      *(half2v*)(M + (size_t)t * KPAD + 2 * wd) = z;
    }
  }
}

// fp16 MFMA GEMM, 64 rows x 128 cols per block, K = kpad (runtime, mult of 32).
// MODE 0: epilogue -> next-layer q (fp16, softmax+entropy).
// MODE 1: epilogue -> cosine sims straight into d_out (fp32; rows are tail indices).
template <int MODE>
__global__ __launch_bounds__(256) void gemm_kernel(const _Float16* __restrict__ M,
                                                   const _Float16* __restrict__ Bt,
                                                   const float* __restrict__ pN,
                                                   void* __restrict__ out_ptr, int n,
                                                   int kpad) {
  __shared__ float smem_f[64 * 132];  // Y tile (fp32, stride 132); staging aliases it
  _Float16* As = (_Float16*)smem_f;           // 64x32 halfs (4KB)
  _Float16* Bs = (_Float16*)(smem_f + 1024);  // 128x32 halfs (8KB)
  int tid = threadIdx.x;
  int wave = tid >> 6, lane = tid & 63;
  int m15 = lane & 15, quad = lane >> 4;
  int n0 = blockIdx.x * 64;
  floatx4 acc[4][2] = {};

  // prototypes sliced per k-quarter (stride 36 -> conflict-free broadcast reads).
  // slice width is P*32 = 576 (R4 bug: was decoded as 512).
  __shared__ float pns[4 * P * 36];
  for (int i = tid; i < 4 * P * 32; i += 256) {
    int s = i / (P * 32), r = i - s * (P * 32);
    int p = r >> 5, kk = r & 31;
    pns[s * (P * 36) + p * 36 + kk] = pN[p * H + s * 32 + kk];
  }

  for (int kt = 0; kt < (kpad >> 5); kt++) {
    int k0 = kt * 32;
    __syncthreads();
    {  // stage A: 64x32 halfs, one 16B load/thread
      int row = tid >> 2, kc = (tid & 3) * 8;
      int gr = n0 + row;
      half8 v = {};
      if (gr < n) v = *(const half8*)(M + (size_t)gr * kpad + k0 + kc);
      *(half8*)(As + row * 32 + kc) = v;
    }
    {  // stage B: 128x32 halfs, two 16B loads/thread
      int col = tid >> 1, kc = (tid & 1) * 16;
      const _Float16* srcp = Bt + (size_t)col * kpad + k0 + kc;
      *(half8*)(Bs + col * 32 + kc) = *(const half8*)srcp;
      *(half8*)(Bs + col * 32 + kc + 8) = *(const half8*)(srcp + 8);
    }
    __syncthreads();
    half8 bfrag0 = *(const half8*)(Bs + (wave * 32 + m15) * 32 + quad * 8);
    half8 bfrag1 = *(const half8*)(Bs + (wave * 32 + 16 + m15) * 32 + quad * 8);
#pragma unroll
    for (int mt = 0; mt < 4; mt++) {
      half8 afrag = *(const half8*)(As + (mt * 16 + m15) * 32 + quad * 8);
      acc[mt][0] = __builtin_amdgcn_mfma_f32_16x16x32_f16(afrag, bfrag0, acc[mt][0], 0, 0, 0);
      acc[mt][1] = __builtin_amdgcn_mfma_f32_16x16x32_f16(afrag, bfrag1, acc[mt][1], 0, 0, 0);
    }
  }
  // D mapping: col = lane&15 (+16 per second mfma), row = quad*4+reg  [HW-verified]
  __syncthreads();  // staging reads done before the Y tile overwrites As/Bs
#pragma unroll
  for (int mt = 0; mt < 4; mt++)
#pragma unroll
    for (int c = 0; c < 2; c++)
#pragma unroll
      for (int reg = 0; reg < 4; reg++)
        smem_f[(mt * 16 + quad * 4 + reg) * 132 + wave * 32 + c * 16 + m15] = acc[mt][c][reg];
  __syncthreads();
  // 4 threads per node, each owns a 32-wide k-slice of the Y row
  int node = tid >> 2, sub = tid & 3;
  int gnode = n0 + node;
  const float* trow = smem_f + node * 132 + sub * 32;
  const float* ps = pns + sub * (P * 36);
  float ss = 0.f;
  float dot[P];
#pragma unroll
  for (int p = 0; p < P; p++) dot[p] = 0.f;
#pragma unroll
  for (int k4 = 0; k4 < 8; k4++) {
    float4 y = *(const float4*)(trow + k4 * 4);
    ss += y.x * y.x + y.y * y.y + y.z * y.z + y.w * y.w;
#pragma unroll
    for (int p = 0; p < P; p++) {
      float4 b = *(const float4*)(ps + p * 36 + k4 * 4);
      dot[p] += y.x * b.x + y.y * b.y + y.z * b.z + y.w * b.w;
    }
  }
  for (int m = 1; m <= 2; m <<= 1) {  // reduce across the 4 subs
    ss += __shfl_xor(ss, m, 64);
#pragma unroll
    for (int p = 0; p < P; p++) dot[p] += __shfl_xor(dot[p], m, 64);
  }
  if (gnode < n) {
    float inv = 1.f / fmaxf(sqrtf(ss), 1e-12f);  // zero rows -> sims 0 (matches ref)
    if (MODE == 1) {
      float* outp = (float*)out_ptr;
      for (int p = sub; p < P; p += 4) outp[(size_t)gnode * P + p] = dot[p] * inv;
    } else {
      float sum = 0.f;
#pragma unroll
      for (int p = 0; p < P; p++) {
        dot[p] = __expf(dot[p] * inv - 1.f);  // sims in [-1,1]: constant shift is exact
        sum += dot[p];
      }
      float isum = 1.f / sum, ent = 0.f;
#pragma unroll
      for (int p = 0; p < P; p++) {
        dot[p] *= isum;
        ent -= dot[p] * __logf(dot[p] + 1e-8f);
      }
      float w = __expf(-ent);
      _Float16* qp = (_Float16*)out_ptr;
      for (int p = sub; p < P; p += 4) qp[(size_t)gnode * P + p] = (_Float16)(w * dot[p]);
    }
  }
}

extern "C" void kernel_launch(void* const* d_in, const int* in_sizes, int n_in,
                              void* d_out, int out_size, void* d_ws, size_t ws_size,
                              hipStream_t stream) {
  const int* eidx = (const int*)d_in[0];
  int E = in_sizes[0] / 2;
  const int* src = eidx;
  const int* dst = eidx + E;
  const int* etype = (const int*)d_in[1];
  const int* tails = (const int*)d_in[2];
  int T = in_sizes[2];
  const float* multi = (const float*)d_in[3];  // [L, 324, 128]
  const float* proto = (const float*)d_in[4];  // [L, 18, 128]
  const float* semb = (const float*)d_in[5];   // [128]
  float* out = (float*)d_out;

  char* w = (char*)d_ws;
  auto alloc = [&](size_t bytes) {
    char* p = w;
    w += (bytes + 255) & ~(size_t)255;
    return p;
  };
  _Float16* q = (_Float16*)alloc((size_t)N_NODES * P * 2);
  float* pNs = (float*)alloc((size_t)3 * P * H * 4);
  float* GS = (float*)alloc((size_t)648 * 4);
  _Float16* Mg = (_Float16*)alloc((size_t)N_NODES * KPAD * 2);
  _Float16* Btg = (_Float16*)alloc((size_t)2 * H * KPAD * 2);
  _Float16* Btl0 = (_Float16*)alloc((size_t)H * K0PAD * 2);
  _Float16* BtD = (_Float16*)alloc((size_t)P * H * 2);
  unsigned* cur = (unsigned*)alloc((size_t)(N_NODES + 1) * 4);  // +1: n0 count
  unsigned* n0list = (unsigned*)alloc((size_t)N0CAP * 4);
  unsigned* ep = (unsigned*)alloc((size_t)N_NODES * ELLW * 4);  // 12.8 MB

  int eb = (E + 255) / 256;  // 3125

  // ---- fused prep: pN, Btg, Btl0/BtD (+inline q0), G/S Grams, cur+n0 zeroing ----
  prep_kernel<<<PREP_MAIN_BLOCKS + PREP_PN_BLOCKS + PREP_GS_BLOCKS, 256, 0, stream>>>(
      multi, proto, semb, pNs, Btg, Btl0, BtD, GS, cur);

  // ---- ELL edge index + src==0 list (partitioned R5 form) ----
  ell_kernel<<<eb * NPART, 256, 0, stream>>>(src, dst, etype, cur, ep, n0list, E);

  // ---- layer 0: fused ballots+Gram epilogue -> q, then parallel n0 patch ----
  histq_kernel<<<(N_NODES + 3) / 4, 256, 0, stream>>>(ep, cur, GS, q, N_NODES);
  patch_kernel<<<(N0CAP + 3) / 4, 256, 0, stream>>>(cur, n0list, ep, Btl0, BtD,
                                                    pNs + (size_t)1 * P * H, q);

  // ---- layer 1: full-node scatter + fused-q GEMM ----
  scatter_kernel<<<(N_NODES + 3) / 4, 256, 0, stream>>>(ep, cur, q, nullptr, Mg, N_NODES);
  gemm_kernel<0><<<(N_NODES + 63) / 64, 256, 0, stream>>>(Mg, Btg, pNs + (size_t)2 * P * H, q,
                                                          N_NODES, KPAD);

  // ---- layer 2: tails only (scatter rows indexed by tail position, GEMM -> d_out) ----
  scatter_kernel<<<(T + 3) / 4, 256, 0, stream>>>(ep, cur, q, tails, Mg, T);
  gemm_kernel<1><<<(T + 63) / 64, 256, 0, stream>>>(Mg, Btg + (size_t)H * KPAD,
                                                    pNs + (size_t)2 * P * H, out, T, KPAD);
}

// Round 9
// 213.957 us; speedup vs baseline: 1.1196x; 1.0792x over previous
//
#include <hip/hip_runtime.h>
#include <hip/hip_bf16.h>

// NBFNet-cluttr forward.
// Algebra exploited:
//  - hidden rows only consumed through cosine sims -> per-row positive scale cancels ->
//    attention denominator dropped (out = M.B unnormalized). Exact.
//  - R20: LAYER-1 SPARSITY. Final output needs q1 only for srcs of tail in-edges
//    (~14K unique of 50K: 1024 tails x Poisson(16), dedup). need_kernel scans tail
//    ELL rows once (atomicExch flag dedup -> compact list, ~16K atomics); scatter1/
//    gemm1 run over the list (device-count-bounded grid, uniform early-exit); gemm1
//    epilogue scatters q1 through the list map. Exact -- q1 elsewhere never read.
//  - layer 0 is a function of per-type in-edge counts ONLY: Y = cnt.C -> collapsed
//    through 18x18 Grams G=C.pN1^T, S=C.C^T (R19); histq produces q directly from
//    ballots (hist+gemm0+3.2MB M roundtrip deleted; savings measured ~2us -> ballot
//    gather dominates that stage, not epilogue).
//  - node-0 correction (~16 nodes w/ src==0 in-edges): patch_kernel, one wave per
//    n0list entry (R16; serial form was 79.5us -- single-wave serialization).
//  - node_pass fused into GEMM epilogue (Y tile stays in LDS; Y never hits HBM).
//  - edge index: fixed-width ELL (64 slots/node), R10 partitioned build. ell is
//    scattered-store/atomic bound (~40us floor: R14 MLP null, R17 nt null, R18
//    single-pass FETCH 37->4.9MB but dur 40->50; WRITE_SIZE invariant ~48MB =
//    E x 64B line write-backs). Degrees Poisson(16): 64 slots = +12sigma.
//  - scatter: 1 wave/row, 3 private LDS slices (15.6KB); 6 edges in flight per
//    18-lane sub (R15); M write-out half2.
//  - GEMM [rows x K]x[K x 128] fp16 MFMA 16x16x32 fp32-acc; rel err ~5e-4 << 1.78e-2.
//  - Ledger: best 230.9 (R19). Fixed harness poison ~89us (2x44.5 fills in-window).
//    ell ~40 measured; other per-kernel budgets are soft (all < fill cutoff 44).
//  - 10 dispatches: prep, ell, histq, patch, need, scatter1, gemm1, scatter2, gemm2.

#define N_NODES 50000
#define H 128
#define P 18
#define RP 324
#define KPAD 352   // 11 * 32
#define K0PAD 32   // Btl0 row stride (18 used; patch only)
#define ELLW 64    // ELL slots per node
#define NPART 8
#define NODES_PER_PART 6250    // 50000 / 8
#define PREP_MAIN_BLOCKS 384   // ceil((2*H*KPAD + H*64)/256) = 98304/256
#define PREP_PN_BLOCKS 14      // 54 proto rows, 4/block
#define PREP_GS_BLOCKS 162     // 648 G/S entries, 4 waves/block
#define N0CAP 1024             // src==0 edge list capacity (E[n0]=16)
#define NEED_CAP 20480         // layer-1 needed-node list cap (E[unique]~14K, +32sigma)

typedef _Float16 half8 __attribute__((ext_vector_type(8)));
typedef _Float16 half2v __attribute__((ext_vector_type(2)));
typedef float floatx4 __attribute__((ext_vector_type(4)));

// Partitioned ELL build (R5 form): block b -> partition b&7, edge chunk b>>3.
// Also appends src==0 edges to n0list (~16 total) for the layer-0 patch.
__global__ __launch_bounds__(256) void ell_kernel(const int* __restrict__ src,
                                                  const int* __restrict__ dst,
                                                  const int* __restrict__ etype,
                                                  unsigned* __restrict__ cur,
                                                  unsigned* __restrict__ ep,
                                                  unsigned* __restrict__ n0list, int E) {
  int part = blockIdx.x & (NPART - 1);
  int i = (blockIdx.x >> 3) * 256 + threadIdx.x;
  if (i >= E) return;
  int d = dst[i];
  int lo = part * NODES_PER_PART;
  if (d < lo || d >= lo + NODES_PER_PART) return;
  int s = src[i];
  int r = etype[i];
  unsigned pos = atomicAdd(&cur[d], 1u);
  if (pos < ELLW)  // Poisson(16): overflow ~impossible; drop, never corrupt
    ep[(size_t)d * ELLW + pos] = (unsigned)s | ((unsigned)r << 20);
  if (s == 0) {  // ~E/N = 16 edges graph-wide
    unsigned ix = atomicAdd(&cur[N_NODES], 1u);
    if (ix < N0CAP) n0list[ix] = (unsigned)d | ((unsigned)r << 20);
  }
}

// Needed-set build (R20): one wave per tail position; mark+append unique srcs of
// tail in-edges. Dedup via atomicExch on nflag; count in cur[N_NODES+1].
__global__ __launch_bounds__(256) void need_kernel(const int* __restrict__ tl,
                                                   const unsigned* __restrict__ ep,
                                                   unsigned* __restrict__ cur,
                                                   unsigned* __restrict__ nflag,
                                                   unsigned* __restrict__ needlist, int T) {
  int wave = threadIdx.x >> 6, lane = threadIdx.x & 63;
  int t = blockIdx.x * 4 + wave;
  if (t >= T) return;
  int nd = tl[t];
  int cnt = (int)cur[nd];
  if (cnt > ELLW) cnt = ELLW;
  if (lane < cnt) {
    unsigned s = ep[(size_t)nd * ELLW + lane] & 0xFFFFFu;
    if (atomicExch(&nflag[s], 1u) == 0u) {
      unsigned ix = atomicAdd(&cur[N_NODES + 1], 1u);
      if (ix < NEED_CAP) needlist[ix] = s;
    }
  }
}

// Fused prep:
//  blocks < PREP_MAIN_BLOCKS: cur+counters+nflag zero, Btg transpose, Btl0/BtD fold
//    (inline per-wave q0 row).
//  next PREP_PN_BLOCKS: pN normalization (4 rows/block).
//  next PREP_GS_BLOCKS: G/S Grams, fp32, 1 entry/wave (reads raw multi/proto only).
__global__ __launch_bounds__(256) void prep_kernel(const float* __restrict__ multi,
                                                   const float* __restrict__ proto,
                                                   const float* __restrict__ semb,
                                                   float* __restrict__ pN,
                                                   _Float16* __restrict__ Btg,
                                                   _Float16* __restrict__ Btl0,
                                                   _Float16* __restrict__ BtD,
                                                   float* __restrict__ GS,
                                                   unsigned* __restrict__ cur,
                                                   unsigned* __restrict__ nflag) {
  int bid = blockIdx.x;
  if (bid >= PREP_MAIN_BLOCKS + PREP_PN_BLOCKS) {
    // G[r][p] = sum_h C[r][h]*pN1[p][h];  S[r][r2] = sum_h C[r][h]*C[r2][h]
    // C[k][h] = qc * sum_q multi0[(k*18+q)*H + h]   (fp32 throughout)
    int wave = threadIdx.x >> 6, lane = threadIdx.x & 63;
    int pi = (bid - PREP_MAIN_BLOCKS - PREP_PN_BLOCKS) * 4 + wave;
    if (pi >= 648) return;
    float pr = 1.f / 18.f, ent0 = 0.f;
#pragma unroll
    for (int p = 0; p < P; p++) ent0 -= pr * __logf(pr + 1e-8f);
    float qc = __expf(-ent0) * pr;
    bool isG = pi < 324;
    int rr = isG ? pi / P : (pi - 324) / P;
    int cc = isG ? pi - rr * P : (pi - 324) - rr * P;
    float ca = 0.f, cb = 0.f;
#pragma unroll
    for (int q2 = 0; q2 < P; q2++) {
      ca += multi[(rr * P + q2) * H + lane];
      cb += multi[(rr * P + q2) * H + lane + 64];
    }
    ca *= qc; cb *= qc;
    float xa, xb, rn = 0.f;
    if (isG) {
      xa = proto[(P + cc) * H + lane];       // layer-1 prototypes
      xb = proto[(P + cc) * H + lane + 64];
      rn = xa * xa + xb * xb;
    } else {
      xa = 0.f; xb = 0.f;
#pragma unroll
      for (int q2 = 0; q2 < P; q2++) {
        xa += multi[(cc * P + q2) * H + lane];
        xb += multi[(cc * P + q2) * H + lane + 64];
      }
      xa *= qc; xb *= qc;
    }
    float dotp = ca * xa + cb * xb;
    for (int m = 32; m > 0; m >>= 1) {
      dotp += __shfl_xor(dotp, m, 64);
      rn += __shfl_xor(rn, m, 64);
    }
    float val = isG ? dotp / fmaxf(sqrtf(rn), 1e-12f) : dotp;
    if (lane == 0) GS[pi] = val;
    return;
  }
  if (bid >= PREP_MAIN_BLOCKS) {
    // normalize the 54 prototype rows: 4 waves/block, 1 row/wave
    int wave = threadIdx.x >> 6, l = threadIdx.x & 63;
    int row = (bid - PREP_MAIN_BLOCKS) * 4 + wave;
    if (row >= 54) return;
    float a = proto[row * H + l], b = proto[row * H + 64 + l];
    float ss = a * a + b * b;
    for (int m = 32; m > 0; m >>= 1) ss += __shfl_xor(ss, m, 64);
    float inv = 1.f / fmaxf(sqrtf(ss), 1e-12f);
    pN[row * H + l] = a * inv;
    pN[row * H + 64 + l] = b * inv;
    return;
  }
  int idx = bid * 256 + threadIdx.x;
  if (idx <= N_NODES + 1) cur[idx] = 0u;  // incl. n0 count + need count
  if (idx < N_NODES) nflag[idx] = 0u;
  if (idx < 2 * H * KPAD) {  // Btg[l-1][h][k] = multi[l][k][h], k-pad to 352
    int l = idx / (H * KPAD), rem = idx - l * (H * KPAD);
    int h = rem / KPAD, k = rem - h * KPAD;
    const float* B = multi + (size_t)(l + 1) * RP * H;
    Btg[idx] = (k < RP) ? (_Float16)B[k * H + h] : (_Float16)0.f;
    return;
  }
  int idx2 = idx - 2 * H * KPAD;  // 2*H*KPAD = 90112, wave-aligned
  if (idx2 >= H * 64) return;     // cut at +8192, wave-aligned
  int h = idx2 >> 6, k = idx2 & 63;  // k == lane (90112 % 64 == 0)
  // inline q0 row (layer-0 q of node 0): full-butterfly -> every lane has all dq[p]
  float s0 = semb[k], s1 = semb[k + 64];
  float ssq = s0 * s0 + s1 * s1;
  float dq[P];
#pragma unroll
  for (int p = 0; p < P; p++) {
    float a = proto[p * H + k], b = proto[p * H + 64 + k];
    float rn = a * a + b * b;
    for (int m = 32; m > 0; m >>= 1) rn += __shfl_xor(rn, m, 64);
    float rinv = 1.f / fmaxf(sqrtf(rn), 1e-12f);
    dq[p] = (s0 * a + s1 * b) * rinv;
  }
  for (int m = 1; m <= 32; m <<= 1) {
    ssq += __shfl_xor(ssq, m, 64);
#pragma unroll
    for (int p = 0; p < P; p++) dq[p] += __shfl_xor(dq[p], m, 64);
  }
  float inv = 1.f / fmaxf(sqrtf(ssq), 1e-12f);
  float sum = 0.f;
#pragma unroll
  for (int p = 0; p < P; p++) {
    dq[p] = __expf(dq[p] * inv - 1.f);  // sims in [-1,1]: constant max-shift is exact
    sum += dq[p];
  }
  float isum = 1.f / sum, ent = 0.f;
#pragma unroll
  for (int p = 0; p < P; p++) {
    dq[p] *= isum;
    ent -= dq[p] * __logf(dq[p] + 1e-8f);
  }
  float w = __expf(-ent);  // q0[p] = w * dq[p]
  float pr = 1.f / 18.f, ent0 = 0.f;
#pragma unroll
  for (int p = 0; p < P; p++) ent0 -= pr * __logf(pr + 1e-8f);
  float qc = __expf(-ent0) * pr;
  if (k < K0PAD) {  // C block: Btl0[h][k] = qc * sum_p multi0[(k,p)][h], k<18
    float v = 0.f;
    if (k < P) {
#pragma unroll
      for (int p = 0; p < P; p++) v += qc * multi[(k * P + p) * H + h];
    }
    Btl0[h * K0PAD + k] = (_Float16)v;
  } else if (k < K0PAD + P) {  // D block (patch): BtD[r][h] = (q0-qc).multi0[r][:][h]
    int r = k - K0PAD;
    float v = 0.f;
#pragma unroll
    for (int p = 0; p < P; p++) v += (w * dq[p] - qc) * multi[(r * P + p) * H + h];
    BtD[r * H + h] = (_Float16)v;
  }
}

// Layer-0 fused hist+epilogue (R19): ballots -> cnt in lanes; dot_p/ss via the
// 18x18 Grams; softmax+entropy in-wave; writes q directly. One node per wave.
__global__ __launch_bounds__(256) void histq_kernel(const unsigned* __restrict__ ep,
                                                    const unsigned* __restrict__ cur,
                                                    const float* __restrict__ GS,
                                                    _Float16* __restrict__ q, int n) {
  __shared__ float gs[648];
  for (int i = threadIdx.x; i < 648; i += 256) gs[i] = GS[i];
  __syncthreads();
  int wave = threadIdx.x >> 6, lane = threadIdx.x & 63;
  int nd = blockIdx.x * 4 + wave;
  if (nd >= n) return;
  int cnt = (int)cur[nd];
  if (cnt > ELLW) cnt = ELLW;
  bool a = lane < cnt;
  unsigned pk = a ? ep[(size_t)nd * ELLW + lane] : 0xFFFFFFFFu;
  int r = (int)(pk >> 20);
  float creg = 0.f;
#pragma unroll
  for (int rr = 0; rr < P; rr++) {
    unsigned long long m = __ballot(a && (r == rr));
    if (lane == rr) creg = (float)__popcll(m);
  }
  // lane p: dot_p = sum_r cnt_r G[r][p];  lane r: t_r = sum_r' cnt_r' S[r'][r]
  float dot = 0.f, t = 0.f;
#pragma unroll
  for (int rr = 0; rr < P; rr++) {
    float c = __shfl(creg, rr, 64);
    if (lane < P) {
      dot += c * gs[rr * P + lane];
      t += c * gs[324 + rr * P + lane];
    }
  }
  float u = (lane < P) ? creg * t : 0.f;  // ss = cnt^T S cnt
  for (int m = 1; m <= 16; m <<= 1) u += __shfl_xor(u, m, 32);
  float ss = u;
  float inv = 1.f / fmaxf(sqrtf(ss), 1e-12f);
  float e = (lane < P) ? __expf(dot * inv - 1.f) : 0.f;  // shift by const 1: exact
  float sum = e;
  for (int m = 1; m <= 16; m <<= 1) sum += __shfl_xor(sum, m, 32);
  float prb = e / sum;
  float term = (lane < P) ? prb * __logf(prb + 1e-8f) : 0.f;
  float ent = term;
  for (int m = 1; m <= 16; m <<= 1) ent += __shfl_xor(ent, m, 32);
  float w = __expf(ent);  // ent accumulated = -entropy
  if (lane < P) q[(size_t)nd * P + lane] = (_Float16)(w * prb);
}

// Layer-0 patch: recompute q for the ~16 nodes with in-edges from node 0.
// One wave per list entry; first occurrence wins; cnt re-balloted from ep (R19).
__global__ __launch_bounds__(256) void patch_kernel(const unsigned* __restrict__ cur,
                                                    const unsigned* __restrict__ n0list,
                                                    const unsigned* __restrict__ ep,
                                                    const _Float16* __restrict__ Btl0,
                                                    const _Float16* __restrict__ BtD,
                                                    const float* __restrict__ pN,
                                                    _Float16* __restrict__ q) {
  int n0 = (int)cur[N_NODES];
  if (n0 > N0CAP) n0 = N0CAP;
  int wave = threadIdx.x >> 6, lane = threadIdx.x & 63;
  int e = blockIdx.x * 4 + wave;
  if (e >= n0) return;
  unsigned pe = n0list[e];
  int d = (int)(pe & 0xFFFFFu);
  for (int e2 = 0; e2 < e; e2++)  // only the first occurrence of d proceeds
    if ((int)(n0list[e2] & 0xFFFFFu) == d) return;
  // re-ballot this node's type counts from its ep row
  int cnt = (int)cur[d];
  if (cnt > ELLW) cnt = ELLW;
  bool a = lane < cnt;
  unsigned pk2 = a ? ep[(size_t)d * ELLW + lane] : 0xFFFFFFFFu;
  int rr0 = (int)(pk2 >> 20);
  float creg = 0.f;
#pragma unroll
  for (int rr = 0; rr < P; rr++) {
    unsigned long long m = __ballot(a && (rr0 == rr));
    if (lane == rr) creg = (float)__popcll(m);
  }
  // base Y[d] = cnt . C  (h = lane, lane+64)
  float ya = 0.f, yb = 0.f;
#pragma unroll
  for (int rr = 0; rr < P; rr++) {
    float c = __shfl(creg, rr, 64);
    ya += c * (float)Btl0[lane * K0PAD + rr];
    yb += c * (float)Btl0[(lane + 64) * K0PAD + rr];
  }
  // + corrections for every src==0 in-edge of d (scan whole list; n0 ~ 16)
  for (int e2 = e; e2 < n0; e2++) {
    unsigned p2 = n0list[e2];
    if ((int)(p2 & 0xFFFFFu) != d) continue;
    int r2 = (int)(p2 >> 20);
    ya += (float)BtD[r2 * H + lane];
    yb += (float)BtD[r2 * H + lane + 64];
  }
  // epilogue f: normalize, cosine sims vs layer-1 protos, softmax, entropy weight
  float ss = ya * ya + yb * yb;
  float dot[P];
#pragma unroll
  for (int p = 0; p < P; p++) dot[p] = ya * pN[p * H + lane] + yb * pN[p * H + lane + 64];
  for (int m = 1; m <= 32; m <<= 1) {
    ss += __shfl_xor(ss, m, 64);
#pragma unroll
    for (int p = 0; p < P; p++) dot[p] += __shfl_xor(dot[p], m, 64);
  }
  float inv = 1.f / fmaxf(sqrtf(ss), 1e-12f);
  float sum = 0.f;
#pragma unroll
  for (int p = 0; p < P; p++) {
    dot[p] = __expf(dot[p] * inv - 1.f);
    sum += dot[p];
  }
  float isum = 1.f / sum, ent = 0.f;
#pragma unroll
  for (int p = 0; p < P; p++) {
    dot[p] *= isum;
    ent -= dot[p] * __logf(dot[p] + 1e-8f);
  }
  float w = __expf(-ent);
  if (lane < P) q[(size_t)d * P + lane] = (_Float16)(w * dot[lane]);
}

// ELL scatter (layers >= 1): one wave per output row; 3 subs of 18 lanes, each with a
// private 324-float LDS slice; 6 edges in flight per sub (R15). q fp16 (36B/edge).
// tl==null: row t = node t. tl!=null: row t = node tl[t]. dc!=null: row count
// = min(n, *dc) (device-side needed-list count, R20).
__global__ __launch_bounds__(256) void scatter_kernel(const unsigned* __restrict__ ep,
                                                      const unsigned* __restrict__ cur,
                                                      const _Float16* __restrict__ q,
                                                      const int* __restrict__ tl,
                                                      const unsigned* __restrict__ dc,
                                                      _Float16* __restrict__ M, int n) {
  __shared__ float sl[4][3 * RP];  // 15.6 KB
  int wave = threadIdx.x >> 6, lane = threadIdx.x & 63;
  int t = blockIdx.x * 4 + wave;
  int neff = n;
  if (dc) {
    int c = (int)dc[0];
    if (c < neff) neff = c;
  }
  float* s0 = sl[wave];
  for (int i = lane; i < 3 * RP; i += 64) s0[i] = 0.f;
  int sub = lane / 18;  // 0,1,2 active; lanes 54-63 idle in the edge loop
  int j = lane - sub * 18;
  bool act = (sub < 3) && (t < neff);
  int cnt = 0;
  size_t b = 0;
  if (t < neff) {
    int nd = tl ? tl[t] : t;
    b = (size_t)nd * ELLW;
    cnt = (int)cur[nd];
    if (cnt > ELLW) cnt = ELLW;
  }
  float* ms = s0 + (sub < 3 ? sub : 0) * RP;
  for (int it = 0; it < cnt; it += 18) {
    bool aa[6];
    unsigned pk[6];
    float qv[6];
#pragma unroll
    for (int u = 0; u < 6; u++) {
      int e = it + 3 * u + sub;
      aa[u] = act && (e < cnt);
      pk[u] = aa[u] ? ep[b + e] : 0u;
    }
#pragma unroll
    for (int u = 0; u < 6; u++)
      qv[u] = aa[u] ? (float)q[(size_t)(pk[u] & 0xFFFFFu) * P + j] : 0.f;
#pragma unroll
    for (int u = 0; u < 6; u++)
      if (aa[u]) ms[(pk[u] >> 20) * P + j] += qv[u];
  }
  if (t < neff) {
    // half2 write-out: 176 words/row; words 0..161 = data, 162..175 = zero pad
    for (int wd = lane; wd < RP / 2; wd += 64) {
      float2 x0 = *(const float2*)(s0 + 2 * wd);
      float2 x1 = *(const float2*)(s0 + RP + 2 * wd);
      float2 x2 = *(const float2*)(s0 + 2 * RP + 2 * wd);
      half2v hv;
      hv[0] = (_Float16)(x0.x + x1.x + x2.x);
      hv[1] = (_Float16)(x0.y + x1.y + x2.y);
      *(half2v*)(M + (size_t)t * KPAD + 2 * wd) = hv;
    }
    for (int wd = RP / 2 + lane; wd < KPAD / 2; wd += 64) {
      half2v z = {};
      *(half2v*)(M + (size_t)t * KPAD + 2 * wd) = z;
    }
  }
}

// fp16 MFMA GEMM, 64 rows x 128 cols per block, K = kpad (runtime, mult of 32).
// MODE 0: epilogue -> next-layer q (fp16, softmax+entropy); map!=null scatters
// row gnode -> node map[gnode] (R20). dc!=null bounds rows by device count.
// MODE 1: epilogue -> cosine sims straight into d_out (fp32; rows = tail positions).
template <int MODE>
__global__ __launch_bounds__(256) void gemm_kernel(const _Float16* __restrict__ M,
                                                   const _Float16* __restrict__ Bt,
                                                   const float* __restrict__ pN,
                                                   const int* __restrict__ map,
                                                   const unsigned* __restrict__ dc,
                                                   void* __restrict__ out_ptr, int n,
                                                   int kpad) {
  int neff = n;
  if (dc) {
    int c = (int)dc[0];
    if (c < neff) neff = c;
  }
  int n0 = blockIdx.x * 64;
  if (n0 >= neff) return;  // uniform early-exit (before any barrier)
  __shared__ float smem_f[64 * 132];  // Y tile (fp32, stride 132); staging aliases it
  _Float16* As = (_Float16*)smem_f;           // 64x32 halfs (4KB)
  _Float16* Bs = (_Float16*)(smem_f + 1024);  // 128x32 halfs (8KB)
  int tid = threadIdx.x;
  int wave = tid >> 6, lane = tid & 63;
  int m15 = lane & 15, quad = lane >> 4;
  floatx4 acc[4][2] = {};

  // prototypes sliced per k-quarter (stride 36 -> conflict-free broadcast reads).
  __shared__ float pns[4 * P * 36];
  for (int i = tid; i < 4 * P * 32; i += 256) {
    int s = i / (P * 32), r = i - s * (P * 32);
    int p = r >> 5, kk = r & 31;
    pns[s * (P * 36) + p * 36 + kk] = pN[p * H + s * 32 + kk];
  }

  for (int kt = 0; kt < (kpad >> 5); kt++) {
    int k0 = kt * 32;
    __syncthreads();
    {  // stage A: 64x32 halfs, one 16B load/thread
      int row = tid >> 2, kc = (tid & 3) * 8;
      int gr = n0 + row;
      half8 v = {};
      if (gr < neff) v = *(const half8*)(M + (size_t)gr * kpad + k0 + kc);
      *(half8*)(As + row * 32 + kc) = v;
    }
    {  // stage B: 128x32 halfs, two 16B loads/thread
      int col = tid >> 1, kc = (tid & 1) * 16;
      const _Float16* srcp = Bt + (size_t)col * kpad + k0 + kc;
      *(half8*)(Bs + col * 32 + kc) = *(const half8*)srcp;
      *(half8*)(Bs + col * 32 + kc + 8) = *(const half8*)(srcp + 8);
    }
    __syncthreads();
    half8 bfrag0 = *(const half8*)(Bs + (wave * 32 + m15) * 32 + quad * 8);
    half8 bfrag1 = *(const half8*)(Bs + (wave * 32 + 16 + m15) * 32 + quad * 8);
#pragma unroll
    for (int mt = 0; mt < 4; mt++) {
      half8 afrag = *(const half8*)(As + (mt * 16 + m15) * 32 + quad * 8);
      acc[mt][0] = __builtin_amdgcn_mfma_f32_16x16x32_f16(afrag, bfrag0, acc[mt][0], 0, 0, 0);
      acc[mt][1] = __builtin_amdgcn_mfma_f32_16x16x32_f16(afrag, bfrag1, acc[mt][1], 0, 0, 0);
    }
  }
  // D mapping: col = lane&15 (+16 per second mfma), row = quad*4+reg  [HW-verified]
  __syncthreads();  // staging reads done before the Y tile overwrites As/Bs
#pragma unroll
  for (int mt = 0; mt < 4; mt++)
#pragma unroll
    for (int c = 0; c < 2; c++)
#pragma unroll
      for (int reg = 0; reg < 4; reg++)
        smem_f[(mt * 16 + quad * 4 + reg) * 132 + wave * 32 + c * 16 + m15] = acc[mt][c][reg];
  __syncthreads();
  // 4 threads per node, each owns a 32-wide k-slice of the Y row
  int node = tid >> 2, sub = tid & 3;
  int gnode = n0 + node;
  const float* trow = smem_f + node * 132 + sub * 32;
  const float* ps = pns + sub * (P * 36);
  float ss = 0.f;
  float dot[P];
#pragma unroll
  for (int p = 0; p < P; p++) dot[p] = 0.f;
#pragma unroll
  for (int k4 = 0; k4 < 8; k4++) {
    float4 y = *(const float4*)(trow + k4 * 4);
    ss += y.x * y.x + y.y * y.y + y.z * y.z + y.w * y.w;
#pragma unroll
    for (int p = 0; p < P; p++) {
      float4 b = *(const float4*)(ps + p * 36 + k4 * 4);
      dot[p] += y.x * b.x + y.y * b.y + y.z * b.z + y.w * b.w;
    }
  }
  for (int m = 1; m <= 2; m <<= 1) {  // reduce across the 4 subs
    ss += __shfl_xor(ss, m, 64);
#pragma unroll
    for (int p = 0; p < P; p++) dot[p] += __shfl_xor(dot[p], m, 64);
  }
  if (gnode < neff) {
    float inv = 1.f / fmaxf(sqrtf(ss), 1e-12f);  // zero rows -> sims 0 (matches ref)
    if (MODE == 1) {
      float* outp = (float*)out_ptr;
      for (int p = sub; p < P; p += 4) outp[(size_t)gnode * P + p] = dot[p] * inv;
    } else {
      float sum = 0.f;
#pragma unroll
      for (int p = 0; p < P; p++) {
        dot[p] = __expf(dot[p] * inv - 1.f);  // sims in [-1,1]: constant shift is exact
        sum += dot[p];
      }
      float isum = 1.f / sum, ent = 0.f;
#pragma unroll
      for (int p = 0; p < P; p++) {
        dot[p] *= isum;
        ent -= dot[p] * __logf(dot[p] + 1e-8f);
      }
      float w = __expf(-ent);
      int gout = map ? map[gnode] : gnode;
      _Float16* qp = (_Float16*)out_ptr;
      for (int p = sub; p < P; p += 4) qp[(size_t)gout * P + p] = (_Float16)(w * dot[p]);
    }
  }
}

extern "C" void kernel_launch(void* const* d_in, const int* in_sizes, int n_in,
                              void* d_out, int out_size, void* d_ws, size_t ws_size,
                              hipStream_t stream) {
  const int* eidx = (const int*)d_in[0];
  int E = in_sizes[0] / 2;
  const int* src = eidx;
  const int* dst = eidx + E;
  const int* etype = (const int*)d_in[1];
  const int* tails = (const int*)d_in[2];
  int T = in_sizes[2];
  const float* multi = (const float*)d_in[3];  // [L, 324, 128]
  const float* proto = (const float*)d_in[4];  // [L, 18, 128]
  const float* semb = (const float*)d_in[5];   // [128]
  float* out = (float*)d_out;

  char* w = (char*)d_ws;
  auto alloc = [&](size_t bytes) {
    char* p = w;
    w += (bytes + 255) & ~(size_t)255;
    return p;
  };
  _Float16* q = (_Float16*)alloc((size_t)N_NODES * P * 2);
  float* pNs = (float*)alloc((size_t)3 * P * H * 4);
  float* GS = (float*)alloc((size_t)648 * 4);
  _Float16* Mg = (_Float16*)alloc((size_t)N_NODES * KPAD * 2);
  _Float16* Btg = (_Float16*)alloc((size_t)2 * H * KPAD * 2);
  _Float16* Btl0 = (_Float16*)alloc((size_t)H * K0PAD * 2);
  _Float16* BtD = (_Float16*)alloc((size_t)P * H * 2);
  unsigned* cur = (unsigned*)alloc((size_t)(N_NODES + 2) * 4);  // +n0cnt, +needcnt
  unsigned* n0list = (unsigned*)alloc((size_t)N0CAP * 4);
  unsigned* nflag = (unsigned*)alloc((size_t)N_NODES * 4);
  unsigned* needlist = (unsigned*)alloc((size_t)NEED_CAP * 4);
  unsigned* ep = (unsigned*)alloc((size_t)N_NODES * ELLW * 4);  // 12.8 MB

  int eb = (E + 255) / 256;  // 3125
  const unsigned* needcnt = cur + N_NODES + 1;

  // ---- fused prep: pN, Btg, Btl0/BtD (+inline q0), G/S Grams, zeroing ----
  prep_kernel<<<PREP_MAIN_BLOCKS + PREP_PN_BLOCKS + PREP_GS_BLOCKS, 256, 0, stream>>>(
      multi, proto, semb, pNs, Btg, Btl0, BtD, GS, cur, nflag);

  // ---- ELL edge index + src==0 list (partitioned R5 form) ----
  ell_kernel<<<eb * NPART, 256, 0, stream>>>(src, dst, etype, cur, ep, n0list, E);

  // ---- layer 0: fused ballots+Gram epilogue -> q, then parallel n0 patch ----
  histq_kernel<<<(N_NODES + 3) / 4, 256, 0, stream>>>(ep, cur, GS, q, N_NODES);
  patch_kernel<<<(N0CAP + 3) / 4, 256, 0, stream>>>(cur, n0list, ep, Btl0, BtD,
                                                    pNs + (size_t)1 * P * H, q);

  // ---- needed set: unique srcs of tail in-edges (~14K of 50K) ----
  need_kernel<<<(T + 3) / 4, 256, 0, stream>>>(tails, ep, cur, nflag, needlist, T);

  // ---- layer 1: scatter+GEMM over the needed list only (R20) ----
  scatter_kernel<<<(NEED_CAP + 3) / 4, 256, 0, stream>>>(ep, cur, q, (const int*)needlist,
                                                         needcnt, Mg, NEED_CAP);
  gemm_kernel<0><<<(NEED_CAP + 63) / 64, 256, 0, stream>>>(
      Mg, Btg, pNs + (size_t)2 * P * H, (const int*)needlist, needcnt, q, NEED_CAP, KPAD);

  // ---- layer 2: tails only (scatter rows indexed by tail position, GEMM -> d_out) ----
  scatter_kernel<<<(T + 3) / 4, 256, 0, stream>>>(ep, cur, q, tails, nullptr, Mg, T);
  gemm_kernel<1><<<(T + 63) / 64, 256, 0, stream>>>(Mg, Btg + (size_t)H * KPAD,
                                                    pNs + (size_t)2 * P * H, nullptr, nullptr,
                                                    out, T, KPAD);
}